// Round 3
// baseline (253.969 us; speedup 1.0000x reference)
//
#include <hip/hip_runtime.h>
#include <hip/hip_bf16.h>

// InputAttention fused: B=256, T=128, F=1024, H=512
// One block per batch row b (grid=256, 1024 threads = 16 waves).
// Phases: [0] stage h|s + pack W1[:, :128] bf16 MFMA A-fragments into LDS
//         [1] c[b,t] = b1[t] + h.W1[t,128:640] + s.W1[t,640:1152]  (fp32)
//         [2] 4 passes: wave (tt, fgrp) computes U[32t x 64f] via mfma_32x32x16_bf16,
//             epilogue tanh+W2 -> e partials -> elds[1024]
//         [3] in-block softmax over f -> out[b, :]

#define B_N 256
#define T_N 128
#define F_N 1024
#define H_N 512
#define IN1 1152

typedef __bf16 bf16x8 __attribute__((ext_vector_type(8)));
typedef float f32x16 __attribute__((ext_vector_type(16)));
typedef float f32x4_t __attribute__((ext_vector_type(4)));

__device__ __forceinline__ float wave_reduce_sum(float v) {
#pragma unroll
  for (int off = 32; off >= 1; off >>= 1) v += __shfl_xor(v, off, 64);
  return v;
}
__device__ __forceinline__ float wave_reduce_max(float v) {
#pragma unroll
  for (int off = 32; off >= 1; off >>= 1) v = fmaxf(v, __shfl_xor(v, off, 64));
  return v;
}
__device__ __forceinline__ float tanh_fast(float u) {
  u = fminf(fmaxf(u, -15.f), 15.f);
  float e2 = __expf(2.f * u);
  return (e2 - 1.f) / (e2 + 1.f);
}
__device__ __forceinline__ unsigned short bfbits(float f) {
  return __builtin_bit_cast(unsigned short, (__bf16)f);
}

__global__ __launch_bounds__(1024) void kFused(const float* __restrict__ h,
                                               const float* __restrict__ s,
                                               const float* __restrict__ x,
                                               const float* __restrict__ W1,
                                               const float* __restrict__ b1,
                                               const float* __restrict__ W2,
                                               const float* __restrict__ b2,
                                               float* __restrict__ out) {
  __shared__ __align__(16) unsigned short w1frag[16384];  // 32 KB, A-fragments
  __shared__ __align__(16) float hs[1024];                // h|s for this b
  __shared__ __align__(16) float cpart[128][8];
  __shared__ __align__(16) float clds[T_N];
  __shared__ __align__(16) float w2lds[T_N];
  __shared__ __align__(16) float epart[4][256];
  __shared__ __align__(16) float elds[F_N];
  __shared__ float rbuf[16];

  const int tid = threadIdx.x;
  const int b = blockIdx.x;

  // ---- phase 0: stage h|s (4 KB) ----
  if (tid < 256) {
    float4 v = (tid < 128) ? reinterpret_cast<const float4*>(h + (size_t)b * H_N)[tid]
                           : reinterpret_cast<const float4*>(s + (size_t)b * H_N)[tid - 128];
    reinterpret_cast<float4*>(hs)[tid] = v;
  }
  // ---- phase 0b: pack W1[:, :128] into fragment order (bit-identical to verified kA_frag) ----
  // frag elem p = ((tt*8+kk)*64 + lane)*8 + j  holds  W1[tt*32+(lane&31)][kk*16+8*(lane>>5)+j]
  {
    const int kk = (tid >> 5) & 7;
    const int tt = tid >> 8;
#pragma unroll
    for (int sub = 0; sub < 2; ++sub) {
      int lane = ((tid << 1) + sub) & 63;
      int t = tt * 32 + (lane & 31);
      int k0 = kk * 16 + 8 * (lane >> 5);
      const float4* wsrc = reinterpret_cast<const float4*>(W1 + (size_t)t * IN1 + k0);
      float4 w0 = wsrc[0], w1v = wsrc[1];
      uint4 pk;
      pk.x = (unsigned)bfbits(w0.x) | ((unsigned)bfbits(w0.y) << 16);
      pk.y = (unsigned)bfbits(w0.z) | ((unsigned)bfbits(w0.w) << 16);
      pk.z = (unsigned)bfbits(w1v.x) | ((unsigned)bfbits(w1v.y) << 16);
      pk.w = (unsigned)bfbits(w1v.z) | ((unsigned)bfbits(w1v.w) << 16);
      *reinterpret_cast<uint4*>(w1frag + ((size_t)((tt * 8 + kk) * 64 + lane) * 8)) = pk;
    }
  }
  __syncthreads();

  // ---- phase 1: c[b,t] fp32 ----
  {
    const int t = tid >> 3, part = tid & 7;
    const float4* wrow = reinterpret_cast<const float4*>(W1 + (size_t)t * IN1 + T_N + part * 128);
    const float4* vrow = reinterpret_cast<const float4*>(hs + part * 128);
    float acc = 0.f;
#pragma unroll 4
    for (int k4 = 0; k4 < 32; ++k4) {
      float4 w = wrow[k4], v = vrow[k4];
      acc += w.x * v.x + w.y * v.y + w.z * v.z + w.w * v.w;
    }
    cpart[t][part] = acc;
  }
  __syncthreads();
  if (tid < 128) {
    float cs = 0.f;
#pragma unroll
    for (int i = 0; i < 8; ++i) cs += cpart[tid][i];
    clds[tid] = cs + b1[tid];
  } else if (tid < 256) {
    w2lds[tid - 128] = W2[tid - 128];
  }
  __syncthreads();

  // ---- phase 2: MFMA passes ----
  const int lane = tid & 63, wave = tid >> 6;
  const int g = lane >> 5, l31 = lane & 31;
  const int tt = wave & 3, fgrp = wave >> 2;
  const bf16x8* af = reinterpret_cast<const bf16x8*>(w1frag);
  const float b2v = b2[0];

  for (int pass = 0; pass < 4; ++pass) {
    const int f0 = pass * 256 + fgrp * 64;
    // float2 view of x[b][.][f0 + 2*l31 .. +2); row stride = 512 float2
    const float2* xb2 = reinterpret_cast<const float2*>(x + (size_t)b * T_N * F_N + f0);
    f32x16 acc0 = {}, acc1 = {};
#pragma unroll
    for (int kk = 0; kk < 8; ++kk) {
      float2 xq[8];
#pragma unroll
      for (int j = 0; j < 8; ++j)
        xq[j] = xb2[(size_t)(kk * 16 + 8 * g + j) * 512 + l31];
      bf16x8 bf0, bf1;
#pragma unroll
      for (int j = 0; j < 8; ++j) {
        bf0[j] = (__bf16)xq[j].x;
        bf1[j] = (__bf16)xq[j].y;
      }
      bf16x8 afr = af[tt * 512 + kk * 64 + lane];
      acc0 = __builtin_amdgcn_mfma_f32_32x32x16_bf16(afr, bf0, acc0, 0, 0, 0);
      acc1 = __builtin_amdgcn_mfma_f32_32x32x16_bf16(afr, bf1, acc1, 0, 0, 0);
    }
    // epilogue: C/D row = (reg&3) + 8*(reg>>2) + 4*g, col = l31 -> f = f0 + 2*l31 + {0,1}
    const int tbase = tt * 32 + 4 * g;
    float ex = 0.f, ey = 0.f;
#pragma unroll
    for (int q = 0; q < 4; ++q) {
      f32x4_t cq = *reinterpret_cast<const f32x4_t*>(&clds[tbase + 8 * q]);
      f32x4_t wq = *reinterpret_cast<const f32x4_t*>(&w2lds[tbase + 8 * q]);
#pragma unroll
      for (int r = 0; r < 4; ++r) {
        int reg = q * 4 + r;
        ex += wq[r] * tanh_fast(acc0[reg] + cq[r]);
        ey += wq[r] * tanh_fast(acc1[reg] + cq[r]);
      }
    }
    ex += __shfl_xor(ex, 32, 64);
    ey += __shfl_xor(ey, 32, 64);
    if (g == 0) {
      float2 e2v = {ex, ey};
      *reinterpret_cast<float2*>(&epart[tt][fgrp * 64 + 2 * l31]) = e2v;
    }
    __syncthreads();
    if (tid < 256) {
      elds[pass * 256 + tid] =
          epart[0][tid] + epart[1][tid] + epart[2][tid] + epart[3][tid] + b2v;
    }
    __syncthreads();
  }

  // ---- phase 3: softmax over f (in-block) ----
  float v = elds[tid];
  float m = wave_reduce_max(v);
  if (lane == 0) rbuf[wave] = m;
  __syncthreads();
  float M = rbuf[0];
#pragma unroll
  for (int i = 1; i < 16; ++i) M = fmaxf(M, rbuf[i]);
  float ev = __expf(v - M);
  float ssum = wave_reduce_sum(ev);
  __syncthreads();
  if (lane == 0) rbuf[wave] = ssum;
  __syncthreads();
  float S = 0.f;
#pragma unroll
  for (int i = 0; i < 16; ++i) S += rbuf[i];
  out[(size_t)b * F_N + tid] = ev / S;
}

extern "C" void kernel_launch(void* const* d_in, const int* in_sizes, int n_in,
                              void* d_out, int out_size, void* d_ws, size_t ws_size,
                              hipStream_t stream) {
  const float* h = (const float*)d_in[0];
  const float* s = (const float*)d_in[1];
  const float* x = (const float*)d_in[2];
  const float* W1 = (const float*)d_in[3];
  const float* b1 = (const float*)d_in[4];
  const float* W2 = (const float*)d_in[5];
  const float* b2 = (const float*)d_in[6];
  float* out = (float*)d_out;

  kFused<<<256, 1024, 0, stream>>>(h, s, x, W1, b1, W2, b2, out);
}

// Round 4
// 242.618 us; speedup vs baseline: 1.0468x; 1.0468x over previous
//
#include <hip/hip_runtime.h>
#include <hip/hip_bf16.h>

// InputAttention: B=256, T=128, F=1024, H=512
//   c[b,t]  = b1[t] + h[b,:]·W1[t,128:640] + s[b,:]·W1[t,640:1152]   (kA_c, fp32)
//   u[f,b,t]= sum_k x[b,k,f]*W1[t,k] + c[b,t]                        (kB_e, bf16 MFMA, x staged in LDS)
//   e[b,f]  = b2 + sum_t W2[t]*tanh(u)                               (kB_e epilogue -> d_out)
//   out[b,f]= softmax_f(e[b,:])                                      (kC, in-place)

#define B_N 256
#define T_N 128
#define F_N 1024
#define H_N 512
#define IN1 1152

typedef __bf16 bf16x8 __attribute__((ext_vector_type(8)));
typedef float f32x16 __attribute__((ext_vector_type(16)));
typedef float f32x4_t __attribute__((ext_vector_type(4)));
typedef unsigned int u32x4 __attribute__((ext_vector_type(4)));

__device__ __forceinline__ float wave_reduce_sum(float v) {
#pragma unroll
  for (int off = 32; off >= 1; off >>= 1) v += __shfl_xor(v, off, 64);
  return v;
}
__device__ __forceinline__ float wave_reduce_max(float v) {
#pragma unroll
  for (int off = 32; off >= 1; off >>= 1) v = fmaxf(v, __shfl_xor(v, off, 64));
  return v;
}
__device__ __forceinline__ float tanh_fast(float u) {
  u = fminf(fmaxf(u, -15.f), 15.f);
  float e2 = __expf(2.f * u);
  return (e2 - 1.f) / (e2 + 1.f);
}
__device__ __forceinline__ unsigned bfbits(float f) {
  return (unsigned)__builtin_bit_cast(unsigned short, (__bf16)f);
}
__device__ __forceinline__ float dot4(float4 a, float4 b) {
  return a.x * b.x + a.y * b.y + a.z * b.z + a.w * b.w;
}

// ---------------- Kernel A: c[b,t] fp32. grid 256 = (t 0..127) x (bhalf 0..1) ----------------
// Wave holds W1[t,128:1152] in registers (16 float4/lane), streams 32 b-rows.
__global__ __launch_bounds__(256) void kA_c(const float* __restrict__ h,
                                            const float* __restrict__ s,
                                            const float* __restrict__ W1,
                                            const float* __restrict__ b1,
                                            float* __restrict__ c) {
  int tid = threadIdx.x, lane = tid & 63, wave = tid >> 6;
  int t = blockIdx.x >> 1, bh = blockIdx.x & 1;
  const float4* wrow = reinterpret_cast<const float4*>(W1 + (size_t)t * IN1 + T_N);
  float4 w0 = wrow[lane], w1v = wrow[64 + lane], w2v = wrow[128 + lane], w3v = wrow[192 + lane];
  float b1t = b1[t];
  int b0 = bh * 128;
#pragma unroll 2
  for (int bi = 0; bi < 32; ++bi) {
    int b = b0 + wave + bi * 4;
    const float4* hr = reinterpret_cast<const float4*>(h + (size_t)b * H_N);
    const float4* sr = reinterpret_cast<const float4*>(s + (size_t)b * H_N);
    float acc = dot4(w0, hr[lane]) + dot4(w1v, hr[64 + lane]) +
                dot4(w2v, sr[lane]) + dot4(w3v, sr[64 + lane]);
    acc = wave_reduce_sum(acc);
    if (lane == 0) c[(size_t)b * T_N + t] = acc + b1t;
  }
}

// ---------------- Kernel A2: pack W1[:, :128] into bf16 MFMA A-fragments (verified) ----------------
// frag elem p = ((tt*8+kk)*64 + lane)*8 + j  holds  W1[tt*32+(lane&31)][kk*16+8*(lane>>5)+j]
__global__ __launch_bounds__(256) void kA_frag(const float* __restrict__ W1,
                                               unsigned short* __restrict__ w1frag) {
  int i = blockIdx.x * 256 + threadIdx.x;  // 0..8191, 2 elems each
  int p0 = i * 2;
  int j = p0 & 7;
  int lane = (p0 >> 3) & 63;
  int kk = (p0 >> 9) & 7;
  int tt = (p0 >> 12) & 3;
  int t = tt * 32 + (lane & 31);
  int k = kk * 16 + 8 * (lane >> 5) + j;
  const float2 w = *reinterpret_cast<const float2*>(W1 + t * IN1 + k);
  *reinterpret_cast<unsigned*>(w1frag + p0) = bfbits(w.x) | (bfbits(w.y) << 16);
}

// ---------------- Kernel B: e[b,f] via MFMA; x converted once into LDS ----------------
// grid 2048 x 256 thr (4 waves). block = (b = bid>>3, fc = bid&7) covering f = fc*128 .. +128.
// LDS X layout (bf16 quads): elem (k,f) at byte (k>>2)*1024 + f*8 + (k&3)*2.
// Wave tt computes U[32t x 128f] as 4 chains (c: f = c*32+l31); B-frag = 2 x ds_read_b64.
__global__ __launch_bounds__(256) void kB_e(const float* __restrict__ x,
                                            const unsigned short* __restrict__ w1frag,
                                            const float* __restrict__ c,
                                            const float* __restrict__ W2,
                                            const float* __restrict__ b2,
                                            float* __restrict__ e) {
  __shared__ __align__(16) unsigned short w1lds[16384];  // 32 KB A-fragments
  __shared__ __align__(16) unsigned char xlds[32768];    // 32 KB X bf16 quads
  __shared__ __align__(16) float clds[T_N];
  __shared__ __align__(16) float w2lds[T_N];
  __shared__ __align__(16) float epart[4][T_N];
  int tid = threadIdx.x;
  int b = blockIdx.x >> 3;
  int fc = blockIdx.x & 7;
  const int fbase = fc * 128;

  {  // stage A fragments (linear 32 KB copy)
    const uint4* src = reinterpret_cast<const uint4*>(w1frag);
    uint4* dst = reinterpret_cast<uint4*>(w1lds);
#pragma unroll
    for (int i = 0; i < 8; ++i) dst[tid + 256 * i] = src[tid + 256 * i];
  }
  {  // stage X: unit u = (kq = u>>6, fp = u&63): 4 float2 rows -> one 16B quad-pair write
    const float* xb = x + (size_t)b * T_N * F_N + fbase;
#pragma unroll
    for (int i = 0; i < 8; ++i) {
      int u = tid + 256 * i;
      int kq = u >> 6, fp = u & 63;
      const float* base = xb + (size_t)(kq * 4) * F_N + fp * 2;
      float2 r0 = *reinterpret_cast<const float2*>(base);
      float2 r1 = *reinterpret_cast<const float2*>(base + F_N);
      float2 r2 = *reinterpret_cast<const float2*>(base + 2 * F_N);
      float2 r3 = *reinterpret_cast<const float2*>(base + 3 * F_N);
      u32x4 pk;
      pk[0] = bfbits(r0.x) | (bfbits(r1.x) << 16);
      pk[1] = bfbits(r2.x) | (bfbits(r3.x) << 16);
      pk[2] = bfbits(r0.y) | (bfbits(r1.y) << 16);
      pk[3] = bfbits(r2.y) | (bfbits(r3.y) << 16);
      *reinterpret_cast<u32x4*>(xlds + kq * 1024 + fp * 16) = pk;
    }
  }
  if (tid < T_N) clds[tid] = c[(size_t)b * T_N + tid];
  else w2lds[tid - T_N] = W2[tid - T_N];
  __syncthreads();

  const int lane = tid & 63, wave = tid >> 6;  // wave = tt
  const int g = lane >> 5, l31 = lane & 31;
  const bf16x8* af = reinterpret_cast<const bf16x8*>(w1lds);

  f32x16 acc0 = {}, acc1 = {}, acc2 = {}, acc3 = {};
#pragma unroll
  for (int kk = 0; kk < 8; ++kk) {
    bf16x8 afr = af[wave * 512 + kk * 64 + lane];
    // B frags: logical k = kk*16 + 8g + j ; quad rows kq = kk*4+2g (+1); f = c*32 + l31
    const unsigned char* bbase = xlds + (kk * 4 + 2 * g) * 1024 + l31 * 8;
#define BFRAG(C)                                                                    \
  ({                                                                                \
    uint2 lo = *reinterpret_cast<const uint2*>(bbase + (C) * 256);                  \
    uint2 hi = *reinterpret_cast<const uint2*>(bbase + (C) * 256 + 1024);           \
    u32x4 q = {lo.x, lo.y, hi.x, hi.y};                                             \
    __builtin_bit_cast(bf16x8, q);                                                  \
  })
    acc0 = __builtin_amdgcn_mfma_f32_32x32x16_bf16(afr, BFRAG(0), acc0, 0, 0, 0);
    acc1 = __builtin_amdgcn_mfma_f32_32x32x16_bf16(afr, BFRAG(1), acc1, 0, 0, 0);
    acc2 = __builtin_amdgcn_mfma_f32_32x32x16_bf16(afr, BFRAG(2), acc2, 0, 0, 0);
    acc3 = __builtin_amdgcn_mfma_f32_32x32x16_bf16(afr, BFRAG(3), acc3, 0, 0, 0);
#undef BFRAG
  }

  // epilogue: C/D row = (reg&3) + 8*(reg>>2) + 4*g (t within tile), col = l31; chain c -> f = c*32+l31
  const int tbase = wave * 32 + 4 * g;
  float es0 = 0.f, es1 = 0.f, es2 = 0.f, es3 = 0.f;
#pragma unroll
  for (int q = 0; q < 4; ++q) {
    f32x4_t cq = *reinterpret_cast<const f32x4_t*>(&clds[tbase + 8 * q]);
    f32x4_t wq = *reinterpret_cast<const f32x4_t*>(&w2lds[tbase + 8 * q]);
#pragma unroll
    for (int r = 0; r < 4; ++r) {
      int reg = q * 4 + r;
      es0 += wq[r] * tanh_fast(acc0[reg] + cq[r]);
      es1 += wq[r] * tanh_fast(acc1[reg] + cq[r]);
      es2 += wq[r] * tanh_fast(acc2[reg] + cq[r]);
      es3 += wq[r] * tanh_fast(acc3[reg] + cq[r]);
    }
  }
  es0 += __shfl_xor(es0, 32, 64);
  es1 += __shfl_xor(es1, 32, 64);
  es2 += __shfl_xor(es2, 32, 64);
  es3 += __shfl_xor(es3, 32, 64);
  if (g == 0) {
    epart[wave][l31] = es0;
    epart[wave][32 + l31] = es1;
    epart[wave][64 + l31] = es2;
    epart[wave][96 + l31] = es3;
  }
  __syncthreads();
  if (tid < T_N) {
    e[(size_t)b * F_N + fbase + tid] =
        epart[0][tid] + epart[1][tid] + epart[2][tid] + epart[3][tid] + b2[0];
  }
}

// ---------------- Kernel C: softmax over f per b, in-place on d_out ----------------
__global__ __launch_bounds__(256) void kC_softmax(float* __restrict__ out) {
  int b = blockIdx.x, tid = threadIdx.x;
  int lane = tid & 63, wid = tid >> 6;
  float* row = out + (size_t)b * F_N;
  float v[4];
#pragma unroll
  for (int q = 0; q < 4; ++q) v[q] = row[tid + 256 * q];
  float m = fmaxf(fmaxf(v[0], v[1]), fmaxf(v[2], v[3]));
  m = wave_reduce_max(m);
  __shared__ float rm[4], rs[4];
  if (lane == 0) rm[wid] = m;
  __syncthreads();
  float M = fmaxf(fmaxf(rm[0], rm[1]), fmaxf(rm[2], rm[3]));
  float ssum = 0.f;
#pragma unroll
  for (int q = 0; q < 4; ++q) {
    v[q] = __expf(v[q] - M);
    ssum += v[q];
  }
  ssum = wave_reduce_sum(ssum);
  if (lane == 0) rs[wid] = ssum;
  __syncthreads();
  float S = rs[0] + rs[1] + rs[2] + rs[3];
  float inv = 1.f / S;
#pragma unroll
  for (int q = 0; q < 4; ++q) row[tid + 256 * q] = v[q] * inv;
}

extern "C" void kernel_launch(void* const* d_in, const int* in_sizes, int n_in,
                              void* d_out, int out_size, void* d_ws, size_t ws_size,
                              hipStream_t stream) {
  const float* h = (const float*)d_in[0];
  const float* s = (const float*)d_in[1];
  const float* x = (const float*)d_in[2];
  const float* W1 = (const float*)d_in[3];
  const float* b1 = (const float*)d_in[4];
  const float* W2 = (const float*)d_in[5];
  const float* b2 = (const float*)d_in[6];
  float* out = (float*)d_out;

  float* c_ws = (float*)d_ws;                                               // 128 KiB
  unsigned short* w1frag = (unsigned short*)((char*)d_ws + B_N * T_N * 4);  // 32 KiB

  kA_c<<<256, 256, 0, stream>>>(h, s, W1, b1, c_ws);
  kA_frag<<<32, 256, 0, stream>>>(W1, w1frag);
  kB_e<<<2048, 256, 0, stream>>>(x, w1frag, c_ws, W2, b2, out);
  kC_softmax<<<256, 256, 0, stream>>>(out);
}

// Round 6
// 233.402 us; speedup vs baseline: 1.0881x; 1.0395x over previous
//
#include <hip/hip_runtime.h>
#include <hip/hip_bf16.h>

// InputAttention: B=256, T=128, F=1024, H=512
//   c[b,t]  = b1[t] + h[b,:]·W1[t,128:640] + s[b,:]·W1[t,640:1152]   (kA_c, fp32)
//   u[f,b,t]= sum_k x[b,k,f]*W1[t,k] + c[b,t]                        (kB_e, bf16 MFMA)
//   e[b,f]  = b2 + sum_t W2[t]*tanh(u)                               (kB_e epilogue -> d_out)
//   out[b,f]= softmax_f(e[b,:])                                      (kC, in-place)

#define B_N 256
#define T_N 128
#define F_N 1024
#define H_N 512
#define IN1 1152

typedef __bf16 bf16x8 __attribute__((ext_vector_type(8)));
typedef float f32x16 __attribute__((ext_vector_type(16)));
typedef float f32x4_t __attribute__((ext_vector_type(4)));
typedef unsigned int u32x4 __attribute__((ext_vector_type(4)));

__device__ __forceinline__ float wave_reduce_sum(float v) {
#pragma unroll
  for (int off = 32; off >= 1; off >>= 1) v += __shfl_xor(v, off, 64);
  return v;
}
__device__ __forceinline__ float wave_reduce_max(float v) {
#pragma unroll
  for (int off = 32; off >= 1; off >>= 1) v = fmaxf(v, __shfl_xor(v, off, 64));
  return v;
}
__device__ __forceinline__ float tanh_fast(float u) {
  u = fminf(fmaxf(u, -15.f), 15.f);
  float e2 = __expf(2.f * u);
  return (e2 - 1.f) / (e2 + 1.f);
}
__device__ __forceinline__ unsigned bfbits(float f) {
  return (unsigned)__builtin_bit_cast(unsigned short, (__bf16)f);
}
__device__ __forceinline__ float dot4(float4 a, float4 b) {
  return a.x * b.x + a.y * b.y + a.z * b.z + a.w * b.w;
}

// ---------------- Kernel A: c[b,t] fp32. grid 512 = (t 0..127) x (bq 0..3) ----------------
// Wave holds W1[t,128:1152] in registers (16 float4/lane), streams 16 b-rows.
__global__ __launch_bounds__(256) void kA_c(const float* __restrict__ h,
                                            const float* __restrict__ s,
                                            const float* __restrict__ W1,
                                            const float* __restrict__ b1,
                                            float* __restrict__ c) {
  int tid = threadIdx.x, lane = tid & 63, wave = tid >> 6;
  int t = blockIdx.x >> 2, bq = blockIdx.x & 3;
  const float4* wrow = reinterpret_cast<const float4*>(W1 + (size_t)t * IN1 + T_N);
  float4 w0 = wrow[lane], w1v = wrow[64 + lane], w2v = wrow[128 + lane], w3v = wrow[192 + lane];
  float b1t = b1[t];
  int b0 = bq * 64;
#pragma unroll 2
  for (int bi = 0; bi < 16; ++bi) {
    int b = b0 + wave + bi * 4;
    const float4* hr = reinterpret_cast<const float4*>(h + (size_t)b * H_N);
    const float4* sr = reinterpret_cast<const float4*>(s + (size_t)b * H_N);
    float acc = dot4(w0, hr[lane]) + dot4(w1v, hr[64 + lane]) +
                dot4(w2v, sr[lane]) + dot4(w3v, sr[64 + lane]);
    acc = wave_reduce_sum(acc);
    if (lane == 0) c[(size_t)b * T_N + t] = acc + b1t;
  }
}

// ---------------- Kernel A2: pack W1[:, :128] into bf16 MFMA A-fragments (verified) ----------------
// frag elem p = ((tt*8+kk)*64 + lane)*8 + j  holds  W1[tt*32+(lane&31)][kk*16+8*(lane>>5)+j]
__global__ __launch_bounds__(256) void kA_frag(const float* __restrict__ W1,
                                               unsigned short* __restrict__ w1frag) {
  int i = blockIdx.x * 256 + threadIdx.x;  // 0..8191, 2 elems each
  int p0 = i * 2;
  int j = p0 & 7;
  int lane = (p0 >> 3) & 63;
  int kk = (p0 >> 9) & 7;
  int tt = (p0 >> 12) & 3;
  int t = tt * 32 + (lane & 31);
  int k = kk * 16 + 8 * (lane >> 5) + j;
  const float2 w = *reinterpret_cast<const float2*>(W1 + t * IN1 + k);
  *reinterpret_cast<unsigned*>(w1frag + p0) = bfbits(w.x) | (bfbits(w.y) << 16);
}

// ---------------- Kernel B: e[b,f] via MFMA; x staged once in LDS (bf16 quads), A from L2 ----------------
// grid 2048 x 256 thr (4 waves). block = (b = bid>>3, fc = bid&7) covering f = fc*128 .. +128.
// LDS X layout: elem (k,f) at byte (k>>2)*1024 + f*8 + (k&3)*2.
// Wave tt computes U[32t x 128f] as 4 chains (c: f = c*32+l31); B-frag = 2 x ds_read_b64.
// A-fragments read directly from global w1frag (L2-resident, 16B/lane coalesced).
__global__ __launch_bounds__(256, 4) void kB_e(const float* __restrict__ x,
                                               const unsigned short* __restrict__ w1frag,
                                               const float* __restrict__ c,
                                               const float* __restrict__ W2,
                                               const float* __restrict__ b2,
                                               float* __restrict__ e) {
  __shared__ __align__(16) unsigned char xlds[32768];  // 32 KB X bf16 quads
  __shared__ __align__(16) float clds[T_N];
  __shared__ __align__(16) float w2lds[T_N];
  __shared__ __align__(16) float epart[4][T_N];
  int tid = threadIdx.x;
  int b = blockIdx.x >> 3;
  int fc = blockIdx.x & 7;
  const int fbase = fc * 128;

  if (tid < T_N) clds[tid] = c[(size_t)b * T_N + tid];
  else w2lds[tid - T_N] = W2[tid - T_N];

  {  // stage X: unit u = (kq = u>>5, fq = u&31): 4 float4 rows -> two 16B quad-pair writes
    const float* xb = x + (size_t)b * T_N * F_N + fbase;
#pragma unroll
    for (int i = 0; i < 4; ++i) {
      int u = tid + 256 * i;
      int kq = u >> 5, fq = u & 31;
      const float* base = xb + (size_t)(kq * 4) * F_N + fq * 4;
      float4 r0 = *reinterpret_cast<const float4*>(base);
      float4 r1 = *reinterpret_cast<const float4*>(base + F_N);
      float4 r2 = *reinterpret_cast<const float4*>(base + 2 * F_N);
      float4 r3 = *reinterpret_cast<const float4*>(base + 3 * F_N);
      u32x4 pa, pb;
      pa[0] = bfbits(r0.x) | (bfbits(r1.x) << 16);
      pa[1] = bfbits(r2.x) | (bfbits(r3.x) << 16);
      pa[2] = bfbits(r0.y) | (bfbits(r1.y) << 16);
      pa[3] = bfbits(r2.y) | (bfbits(r3.y) << 16);
      pb[0] = bfbits(r0.z) | (bfbits(r1.z) << 16);
      pb[1] = bfbits(r2.z) | (bfbits(r3.z) << 16);
      pb[2] = bfbits(r0.w) | (bfbits(r1.w) << 16);
      pb[3] = bfbits(r2.w) | (bfbits(r3.w) << 16);
      unsigned char* dst = xlds + kq * 1024 + fq * 32;
      *reinterpret_cast<u32x4*>(dst) = pa;
      *reinterpret_cast<u32x4*>(dst + 16) = pb;
    }
  }
  __syncthreads();

  const int lane = tid & 63, wave = tid >> 6;  // wave = tt
  const int g = lane >> 5, l31 = lane & 31;
  const bf16x8* af = reinterpret_cast<const bf16x8*>(w1frag);

  f32x16 acc0 = {}, acc1 = {}, acc2 = {}, acc3 = {};
#pragma unroll 4
  for (int kk = 0; kk < 8; ++kk) {
    bf16x8 afr = af[wave * 512 + kk * 64 + lane];
    // B frags: logical k = kk*16 + 8g + j ; quad rows kq = kk*4+2g (+1); f = c*32 + l31
    const unsigned char* bbase = xlds + (kk * 4 + 2 * g) * 1024 + l31 * 8;
#define BFRAG(C)                                                                    \
  ({                                                                                \
    uint2 lo = *reinterpret_cast<const uint2*>(bbase + (C) * 256);                  \
    uint2 hi = *reinterpret_cast<const uint2*>(bbase + (C) * 256 + 1024);           \
    u32x4 q = {lo.x, lo.y, hi.x, hi.y};                                             \
    __builtin_bit_cast(bf16x8, q);                                                  \
  })
    acc0 = __builtin_amdgcn_mfma_f32_32x32x16_bf16(afr, BFRAG(0), acc0, 0, 0, 0);
    acc1 = __builtin_amdgcn_mfma_f32_32x32x16_bf16(afr, BFRAG(1), acc1, 0, 0, 0);
    acc2 = __builtin_amdgcn_mfma_f32_32x32x16_bf16(afr, BFRAG(2), acc2, 0, 0, 0);
    acc3 = __builtin_amdgcn_mfma_f32_32x32x16_bf16(afr, BFRAG(3), acc3, 0, 0, 0);
#undef BFRAG
  }

  // epilogue: C/D row = (reg&3) + 8*(reg>>2) + 4*g (t within tile), col = l31; chain c -> f = c*32+l31
  const int tbase = wave * 32 + 4 * g;
  float es0 = 0.f, es1 = 0.f, es2 = 0.f, es3 = 0.f;
#pragma unroll
  for (int q = 0; q < 4; ++q) {
    f32x4_t cq = *reinterpret_cast<const f32x4_t*>(&clds[tbase + 8 * q]);
    f32x4_t wq = *reinterpret_cast<const f32x4_t*>(&w2lds[tbase + 8 * q]);
#pragma unroll
    for (int r = 0; r < 4; ++r) {
      int reg = q * 4 + r;
      es0 += wq[r] * tanh_fast(acc0[reg] + cq[r]);
      es1 += wq[r] * tanh_fast(acc1[reg] + cq[r]);
      es2 += wq[r] * tanh_fast(acc2[reg] + cq[r]);
      es3 += wq[r] * tanh_fast(acc3[reg] + cq[r]);
    }
  }
  es0 += __shfl_xor(es0, 32, 64);
  es1 += __shfl_xor(es1, 32, 64);
  es2 += __shfl_xor(es2, 32, 64);
  es3 += __shfl_xor(es3, 32, 64);
  if (g == 0) {
    epart[wave][l31] = es0;
    epart[wave][32 + l31] = es1;
    epart[wave][64 + l31] = es2;
    epart[wave][96 + l31] = es3;
  }
  __syncthreads();
  if (tid < T_N) {
    e[(size_t)b * F_N + fbase + tid] =
        epart[0][tid] + epart[1][tid] + epart[2][tid] + epart[3][tid] + b2[0];
  }
}

// ---------------- Kernel C: softmax over f per b, in-place on d_out ----------------
__global__ __launch_bounds__(256) void kC_softmax(float* __restrict__ out) {
  int b = blockIdx.x, tid = threadIdx.x;
  int lane = tid & 63, wid = tid >> 6;
  float* row = out + (size_t)b * F_N;
  float v[4];
#pragma unroll
  for (int q = 0; q < 4; ++q) v[q] = row[tid + 256 * q];
  float m = fmaxf(fmaxf(v[0], v[1]), fmaxf(v[2], v[3]));
  m = wave_reduce_max(m);
  __shared__ float rm[4], rs[4];
  if (lane == 0) rm[wid] = m;
  __syncthreads();
  float M = fmaxf(fmaxf(rm[0], rm[1]), fmaxf(rm[2], rm[3]));
  float ssum = 0.f;
#pragma unroll
  for (int q = 0; q < 4; ++q) {
    v[q] = __expf(v[q] - M);
    ssum += v[q];
  }
  ssum = wave_reduce_sum(ssum);
  if (lane == 0) rs[wid] = ssum;
  __syncthreads();
  float S = rs[0] + rs[1] + rs[2] + rs[3];
  float inv = 1.f / S;
#pragma unroll
  for (int q = 0; q < 4; ++q) row[tid + 256 * q] = v[q] * inv;
}

extern "C" void kernel_launch(void* const* d_in, const int* in_sizes, int n_in,
                              void* d_out, int out_size, void* d_ws, size_t ws_size,
                              hipStream_t stream) {
  const float* h = (const float*)d_in[0];
  const float* s = (const float*)d_in[1];
  const float* x = (const float*)d_in[2];
  const float* W1 = (const float*)d_in[3];
  const float* b1 = (const float*)d_in[4];
  const float* W2 = (const float*)d_in[5];
  const float* b2 = (const float*)d_in[6];
  float* out = (float*)d_out;

  float* c_ws = (float*)d_ws;                                               // 128 KiB
  unsigned short* w1frag = (unsigned short*)((char*)d_ws + B_N * T_N * 4);  // 32 KiB

  kA_c<<<512, 256, 0, stream>>>(h, s, W1, b1, c_ws);
  kA_frag<<<32, 256, 0, stream>>>(W1, w1frag);
  kB_e<<<2048, 256, 0, stream>>>(x, w1frag, c_ws, W2, b2, out);
  kC_softmax<<<256, 256, 0, stream>>>(out);
}

// Round 8
// 224.999 us; speedup vs baseline: 1.1288x; 1.0373x over previous
//
#include <hip/hip_runtime.h>
#include <hip/hip_bf16.h>

// InputAttention: B=256, T=128, F=1024, H=512
//   c[b,t]  = b1[t] + h[b,:]·W1[t,128:640] + s[b,:]·W1[t,640:1152]   (kAB, fp32)
//   W1[:, :128] packed to bf16 MFMA A-fragments                      (kAB, tail blocks)
//   u[f,b,t]= sum_k x[b,k,f]*W1[t,k] + c[b,t]                        (kB_e, bf16 MFMA)
//   e[b,f]  = b2 + sum_t W2[t]*tanh(u)                               (kB_e epilogue -> d_out)
//   out[b,f]= softmax_f(e[b,:])                                      (kC, in-place)

#define B_N 256
#define T_N 128
#define F_N 1024
#define H_N 512
#define IN1 1152

typedef __bf16 bf16x8 __attribute__((ext_vector_type(8)));
typedef float f32x16 __attribute__((ext_vector_type(16)));
typedef float f32x4_t __attribute__((ext_vector_type(4)));
typedef unsigned int u32x4 __attribute__((ext_vector_type(4)));

__device__ __forceinline__ float wave_reduce_sum(float v) {
#pragma unroll
  for (int off = 32; off >= 1; off >>= 1) v += __shfl_xor(v, off, 64);
  return v;
}
__device__ __forceinline__ float wave_reduce_max(float v) {
#pragma unroll
  for (int off = 32; off >= 1; off >>= 1) v = fmaxf(v, __shfl_xor(v, off, 64));
  return v;
}
__device__ __forceinline__ float tanh_fast(float u) {
  u = fminf(fmaxf(u, -15.f), 15.f);
  float e2 = __expf(2.f * u);
  return (e2 - 1.f) / (e2 + 1.f);
}
__device__ __forceinline__ unsigned bfbits(float f) {
  return (unsigned)__builtin_bit_cast(unsigned short, (__bf16)f);
}
__device__ __forceinline__ float dot4(float4 a, float4 b) {
  return a.x * b.x + a.y * b.y + a.z * b.z + a.w * b.w;
}

// ---------------- Kernel AB: c[b,t] (blocks 0..511) + W1 frag pack (blocks 512..543) ----------
// kA_c part: block = (t = bid>>2, bq = bid&3); wave holds W1[t,128:1152] in regs, streams 16 b.
// kA_frag part: frag elem p = ((tt*8+kk)*64 + lane)*8 + j = W1[tt*32+(lane&31)][kk*16+8*(lane>>5)+j]
__global__ __launch_bounds__(256) void kAB(const float* __restrict__ h,
                                           const float* __restrict__ s,
                                           const float* __restrict__ W1,
                                           const float* __restrict__ b1,
                                           float* __restrict__ c,
                                           unsigned short* __restrict__ w1frag) {
  int tid = threadIdx.x;
  if (blockIdx.x < 512) {
    int lane = tid & 63, wave = tid >> 6;
    int t = blockIdx.x >> 2, bq = blockIdx.x & 3;
    const float4* wrow = reinterpret_cast<const float4*>(W1 + (size_t)t * IN1 + T_N);
    float4 w0 = wrow[lane], w1v = wrow[64 + lane], w2v = wrow[128 + lane], w3v = wrow[192 + lane];
    float b1t = b1[t];
    int b0 = bq * 64;
#pragma unroll 2
    for (int bi = 0; bi < 16; ++bi) {
      int b = b0 + wave + bi * 4;
      const float4* hr = reinterpret_cast<const float4*>(h + (size_t)b * H_N);
      const float4* sr = reinterpret_cast<const float4*>(s + (size_t)b * H_N);
      float acc = dot4(w0, hr[lane]) + dot4(w1v, hr[64 + lane]) +
                  dot4(w2v, sr[lane]) + dot4(w3v, sr[64 + lane]);
      acc = wave_reduce_sum(acc);
      if (lane == 0) c[(size_t)b * T_N + t] = acc + b1t;
    }
  } else {
    int i = (blockIdx.x - 512) * 256 + tid;  // 0..8191, 2 elems each
    int p0 = i * 2;
    int j = p0 & 7;
    int lane = (p0 >> 3) & 63;
    int kk = (p0 >> 9) & 7;
    int tt = (p0 >> 12) & 3;
    int t = tt * 32 + (lane & 31);
    int k = kk * 16 + 8 * (lane >> 5) + j;
    const float2 w = *reinterpret_cast<const float2*>(W1 + t * IN1 + k);
    *reinterpret_cast<unsigned*>(w1frag + p0) = bfbits(w.x) | (bfbits(w.y) << 16);
  }
}

// ---------------- Kernel B: e[b,f] via MFMA; x staged in LDS (bf16 quads, 64-f tile) -----------
// grid 4096 x 256 thr (4 waves). block = (b = bid>>4, fc = bid&15) covering f = fc*64 .. +64.
// LDS X layout: elem (k,f) at byte (k>>2)*512 + f*8 + (k&3)*2   (16 KB).
// Wave tt computes U[32t x 64f] as 2 chains (c: f = c*32+l31); B-frag = 2 x ds_read_b64.
// A-fragments read directly from global w1frag (L2-resident, 16B/lane coalesced).
__global__ __launch_bounds__(256, 6) void kB_e(const float* __restrict__ x,
                                               const unsigned short* __restrict__ w1frag,
                                               const float* __restrict__ c,
                                               const float* __restrict__ W2,
                                               const float* __restrict__ b2,
                                               float* __restrict__ e) {
  __shared__ __align__(16) unsigned char xlds[16384];  // 16 KB X bf16 quads
  __shared__ __align__(16) float clds[T_N];
  __shared__ __align__(16) float w2lds[T_N];
  __shared__ __align__(16) float epart[4][64];
  int tid = threadIdx.x;
  int b = blockIdx.x >> 4;
  int fc = blockIdx.x & 15;
  const int fbase = fc * 64;

  if (tid < T_N) clds[tid] = c[(size_t)b * T_N + tid];
  else w2lds[tid - T_N] = W2[tid - T_N];

  {  // stage X: unit u = (kq = u>>4, fq = u&15): 4 float4 rows -> two 16B quad-pair writes
    const float* xb = x + (size_t)b * T_N * F_N + fbase;
#pragma unroll
    for (int i = 0; i < 2; ++i) {
      int u = tid + 256 * i;
      int kq = u >> 4, fq = u & 15;
      const float* base = xb + (size_t)(kq * 4) * F_N + fq * 4;
      float4 r0 = *reinterpret_cast<const float4*>(base);
      float4 r1 = *reinterpret_cast<const float4*>(base + F_N);
      float4 r2 = *reinterpret_cast<const float4*>(base + 2 * F_N);
      float4 r3 = *reinterpret_cast<const float4*>(base + 3 * F_N);
      u32x4 pa, pb;
      pa[0] = bfbits(r0.x) | (bfbits(r1.x) << 16);
      pa[1] = bfbits(r2.x) | (bfbits(r3.x) << 16);
      pa[2] = bfbits(r0.y) | (bfbits(r1.y) << 16);
      pa[3] = bfbits(r2.y) | (bfbits(r3.y) << 16);
      pb[0] = bfbits(r0.z) | (bfbits(r1.z) << 16);
      pb[1] = bfbits(r2.z) | (bfbits(r3.z) << 16);
      pb[2] = bfbits(r0.w) | (bfbits(r1.w) << 16);
      pb[3] = bfbits(r2.w) | (bfbits(r3.w) << 16);
      unsigned char* dst = xlds + kq * 512 + fq * 32;
      *reinterpret_cast<u32x4*>(dst) = pa;
      *reinterpret_cast<u32x4*>(dst + 16) = pb;
    }
  }
  __syncthreads();

  const int lane = tid & 63, wave = tid >> 6;  // wave = tt
  const int g = lane >> 5, l31 = lane & 31;
  const bf16x8* af = reinterpret_cast<const bf16x8*>(w1frag);

  f32x16 acc0 = {}, acc1 = {};
#pragma unroll
  for (int kk = 0; kk < 8; ++kk) {
    bf16x8 afr = af[wave * 512 + kk * 64 + lane];
    // B frags: logical k = kk*16 + 8g + j ; quad rows kq = kk*4+2g (+1); f = c*32 + l31
    const unsigned char* bbase = xlds + (kk * 4 + 2 * g) * 512 + l31 * 8;
#define BFRAG(C)                                                                    \
  ({                                                                                \
    uint2 lo = *reinterpret_cast<const uint2*>(bbase + (C) * 256);                  \
    uint2 hi = *reinterpret_cast<const uint2*>(bbase + (C) * 256 + 512);            \
    u32x4 q = {lo.x, lo.y, hi.x, hi.y};                                             \
    __builtin_bit_cast(bf16x8, q);                                                  \
  })
    acc0 = __builtin_amdgcn_mfma_f32_32x32x16_bf16(afr, BFRAG(0), acc0, 0, 0, 0);
    acc1 = __builtin_amdgcn_mfma_f32_32x32x16_bf16(afr, BFRAG(1), acc1, 0, 0, 0);
#undef BFRAG
  }

  // epilogue: C/D row = (reg&3) + 8*(reg>>2) + 4*g (t within tile), col = l31; chain c -> f = c*32+l31
  const int tbase = wave * 32 + 4 * g;
  float es0 = 0.f, es1 = 0.f;
#pragma unroll
  for (int q = 0; q < 4; ++q) {
    f32x4_t cq = *reinterpret_cast<const f32x4_t*>(&clds[tbase + 8 * q]);
    f32x4_t wq = *reinterpret_cast<const f32x4_t*>(&w2lds[tbase + 8 * q]);
#pragma unroll
    for (int r = 0; r < 4; ++r) {
      int reg = q * 4 + r;
      es0 += wq[r] * tanh_fast(acc0[reg] + cq[r]);
      es1 += wq[r] * tanh_fast(acc1[reg] + cq[r]);
    }
  }
  es0 += __shfl_xor(es0, 32, 64);
  es1 += __shfl_xor(es1, 32, 64);
  if (g == 0) {
    epart[wave][l31] = es0;
    epart[wave][32 + l31] = es1;
  }
  __syncthreads();
  if (tid < 64) {
    e[(size_t)b * F_N + fbase + tid] =
        epart[0][tid] + epart[1][tid] + epart[2][tid] + epart[3][tid] + b2[0];
  }
}

// ---------------- Kernel C: softmax over f per b, in-place on d_out ----------------
__global__ __launch_bounds__(256) void kC_softmax(float* __restrict__ out) {
  int b = blockIdx.x, tid = threadIdx.x;
  int lane = tid & 63, wid = tid >> 6;
  float* row = out + (size_t)b * F_N;
  float v[4];
#pragma unroll
  for (int q = 0; q < 4; ++q) v[q] = row[tid + 256 * q];
  float m = fmaxf(fmaxf(v[0], v[1]), fmaxf(v[2], v[3]));
  m = wave_reduce_max(m);
  __shared__ float rm[4], rs[4];
  if (lane == 0) rm[wid] = m;
  __syncthreads();
  float M = fmaxf(fmaxf(rm[0], rm[1]), fmaxf(rm[2], rm[3]));
  float ssum = 0.f;
#pragma unroll
  for (int q = 0; q < 4; ++q) {
    v[q] = __expf(v[q] - M);
    ssum += v[q];
  }
  ssum = wave_reduce_sum(ssum);
  if (lane == 0) rs[wid] = ssum;
  __syncthreads();
  float S = rs[0] + rs[1] + rs[2] + rs[3];
  float inv = 1.f / S;
#pragma unroll
  for (int q = 0; q < 4; ++q) row[tid + 256 * q] = v[q] * inv;
}

extern "C" void kernel_launch(void* const* d_in, const int* in_sizes, int n_in,
                              void* d_out, int out_size, void* d_ws, size_t ws_size,
                              hipStream_t stream) {
  const float* h = (const float*)d_in[0];
  const float* s = (const float*)d_in[1];
  const float* x = (const float*)d_in[2];
  const float* W1 = (const float*)d_in[3];
  const float* b1 = (const float*)d_in[4];
  const float* W2 = (const float*)d_in[5];
  const float* b2 = (const float*)d_in[6];
  float* out = (float*)d_out;

  float* c_ws = (float*)d_ws;                                               // 128 KiB
  unsigned short* w1frag = (unsigned short*)((char*)d_ws + B_N * T_N * 4);  // 32 KiB

  kAB<<<544, 256, 0, stream>>>(h, s, W1, b1, c_ws, w1frag);
  kB_e<<<4096, 256, 0, stream>>>(x, w1frag, c_ws, W2, b2, out);
  kC_softmax<<<256, 256, 0, stream>>>(out);
}